// Round 4
// baseline (608.241 us; speedup 1.0000x reference)
//
#include <hip/hip_runtime.h>

#define T_LEN 1024
#define B_SZ  4096
#define CHUNK 16                      // timesteps per LDS ring buffer
#define NCHUNK (T_LEN / CHUNK)        // 64 chunks
#define NC 4                          // independent batch chains per lane

// DPP controls (gfx9/CDNA).
// quad_perm xor patterns + broadcasts are direction-unambiguous.
// row_ror convention VERIFIED BY EVIDENCE (prior rounds): ror:12 reads lane+4,
// ror:8 reads lane+8, ror:4 reads lane+12. row_shr scan (lane i reads i-n)
// anchored by LLVM AMDGPUAtomicOptimizer.
#define DPP_QP(a,b,c,d) ((a)|((b)<<2)|((c)<<4)|((d)<<6))
#define DPP_QPX1 DPP_QP(1,0,3,2)   // lane ^ 1 (within quad)
#define DPP_QPX2 DPP_QP(2,3,0,1)   // lane ^ 2
#define DPP_QPX3 DPP_QP(3,2,1,0)   // lane ^ 3
#define DPP_BCAST0 DPP_QP(0,0,0,0) // all quad lanes read quad lane 0
#define DPP_BCAST1 DPP_QP(1,1,1,1)
#define DPP_BCAST2 DPP_QP(2,2,2,2)
#define DPP_BCAST3 DPP_QP(3,3,3,3)
#define DPP_ROW_SHR(n) (0x110|(n))
#define DPP_ROW_ROR(n) (0x120|(n))

template <int CTRL>
__device__ __forceinline__ float dppf(float x) {
  return __int_as_float(__builtin_amdgcn_update_dpp(
      0, __float_as_int(x), CTRL, 0xF, 0xF, true));
}
// Scan helper: invalid source lanes receive identity 1.0f (old operand,
// bound_ctrl=false => keep old). Removes the (w>=k) cndmask guards.
template <int CTRL>
__device__ __forceinline__ float dppf_id1(float x) {
  return __int_as_float(__builtin_amdgcn_update_dpp(
      0x3f800000, __float_as_int(x), CTRL, 0xF, 0xF, false));
}

// Lane layout within each 16-lane group:
//   lane16 = w*4 + g   (w = wire/hidden 0..3 bits[3:2],
//                       g = gate 0=f,1=i,2=g,3=o AND x-quarter, bits[1:0])
// qlayer closed form: out_w = prod_{j<=w} cos(theta_j), theta = W.[x,h]+b+phi
//
// ILP on the serial chain: each consumer lane carries NC=4 independent batch
// recurrences; 4 chains interleave in the pipeline so chain latency is paid
// once per 4 timesteps. 2 producer waves x 2 chains feed a double-buffered
// LDS ring. Block = 192 threads (wave0 consumer, waves1-2 producers).
//
// THIS ROUND: unified chunk loop with a SINGLE textual __syncthreads()
// executed by all waves (divergent-barrier pattern removed — it is UB in the
// HIP model and is the only plausible kernel-side cause of the container
// hangs). Pipelining preserved: producer fills chunk c pre-barrier, consumer
// drains it post-barrier while the producer races ahead to chunk c+1;
// buffer (c&1) is rewritten only after barrier c+1, by which point the
// consumer has finished chunk c.
__global__ void __launch_bounds__(192, 1) qlstm_65481071402744_kernel(
    const float* __restrict__ x,
    const float* __restrict__ Wf, const float* __restrict__ bfv,
    const float* __restrict__ Wi, const float* __restrict__ biv,
    const float* __restrict__ Wg, const float* __restrict__ bgv,
    const float* __restrict__ Wo, const float* __restrict__ bov,
    const float* __restrict__ rxf, const float* __restrict__ rxi,
    const float* __restrict__ rxg, const float* __restrict__ rxo,
    float* __restrict__ out) {
  __shared__ float zbuf[2][CHUNK][64 * NC];  // 32 KiB, lane-consecutive dwords

  const int tid = threadIdx.x;
  const int wv = tid >> 6;        // 0 = consumer, 1..2 = producers
  const int lane = tid & 63;
  const int g = lane & 3;         // gate index AND x-quarter index
  const int w = (lane >> 2) & 3;  // wire index
  const int bq = lane >> 4;       // batch slot within wave (0..3)
  const int b0 = (blockIdx.x << 4) + bq;  // chain j handles batch b0 + 4*j
  const bool prod = (wv != 0);

  auto Wsel = [&](int gg) -> const float* {
    return gg == 0 ? Wf : gg == 1 ? Wi : gg == 2 ? Wg : Wo;
  };
  const float* bown = g == 0 ? bfv : g == 1 ? biv : g == 2 ? bgv : bov;
  const float* rxown = g == 0 ? rxf : g == 1 ? rxi : g == 2 ? rxg : rxo;
  constexpr float INV2PI = 0.15915494309189535f;
  constexpr float L2E = 1.4426950408889634f;

  // ---------------- producer state (waves 1-2) ---------------------------
  // x-part weights: lane (w,g) computes p[j] = partial of (gate g^j, wire w)
  // over x-quarter [4g, 4g+4); xor-reduce gathers. Pre-scaled by 1/2pi.
  float Wxp[4][4];
  float zinit = 0.0f;
  const float4 *xpA = nullptr, *xpB = nullptr;
  float4 xrA[8], xrB[8];
  int col = 0;
  if (prod) {
    const int pw = wv - 1;  // 0 or 1; handles chains 2*pw and 2*pw+1
#pragma unroll
    for (int j = 0; j < 4; ++j) {
      const float* Wt = Wsel(g ^ j);
#pragma unroll
      for (int d = 0; d < 4; ++d)
        Wxp[j][d] = Wt[w * 20 + (g << 2) + d] * INV2PI;
    }
    zinit = (bown[w] + rxown[w]) * INV2PI;  // bias + RX phase (rev)
    xpA = (const float4*)x + ((size_t)(b0 + 4 * (2 * pw + 0)) << 2) + g;
    xpB = (const float4*)x + ((size_t)(b0 + 4 * (2 * pw + 1)) << 2) + g;
    // 8-deep register prefetch ring per chain (covers HBM latency)
#pragma unroll
    for (int u = 0; u < 8; ++u) {
      xrA[u] = xpA[(size_t)u * (B_SZ * 4)];
      xrB[u] = xpB[(size_t)u * (B_SZ * 4)];
    }
    col = (pw << 7) + lane;  // chain 2*pw column base
  }

  auto xdot = [&](const float4& xq) -> float {
    float p0 = fmaf(Wxp[0][0], xq.x, zinit);
    p0 = fmaf(Wxp[0][1], xq.y, p0);
    p0 = fmaf(Wxp[0][2], xq.z, p0);
    p0 = fmaf(Wxp[0][3], xq.w, p0);
    float p1 = fmaf(Wxp[1][3], xq.w,
               fmaf(Wxp[1][2], xq.z,
               fmaf(Wxp[1][1], xq.y, Wxp[1][0] * xq.x)));
    float p2 = fmaf(Wxp[2][3], xq.w,
               fmaf(Wxp[2][2], xq.z,
               fmaf(Wxp[2][1], xq.y, Wxp[2][0] * xq.x)));
    float p3 = fmaf(Wxp[3][3], xq.w,
               fmaf(Wxp[3][2], xq.z,
               fmaf(Wxp[3][1], xq.y, Wxp[3][0] * xq.x)));
    // xor rotate-reduce within quad: full x-dot + bias + phase (rev)
    const float zx = (p0 + dppf<DPP_QPX1>(p1)) +
                     (dppf<DPP_QPX2>(p2) + dppf<DPP_QPX3>(p3));
    return __builtin_amdgcn_fractf(zx);  // pre-fract (cos is 1-periodic)
  };

  // ---------------- consumer state (wave 0) ------------------------------
  const float* Wown = Wsel(g);
  float Whs[4];
#pragma unroll
  for (int k = 0; k < 4; ++k)
    Whs[k] = Wown[w * 20 + 16 + ((w + k) & 3)] * INV2PI;
  const bool isG = (g == 2);                      // tanh gate
  const float nlscale = isG ? -2.0f * L2E : -L2E; // exp2 scale
  const float nla = isG ? 2.0f : 1.0f;            // post-rcp fma a
  const float nlb = isG ? -1.0f : 0.0f;           // post-rcp fma b
  float hx[NC], cx[NC];
  float* outp[NC];
#pragma unroll
  for (int j = 0; j < NC; ++j) {
    hx[j] = 0.0f;
    cx[j] = 0.0f;
    outp[j] = out + ((size_t)(b0 + 4 * j) << 2) + w;
  }

  // ---------------- unified chunk loop: ONE textual barrier --------------
  for (int c = 0; c < NCHUNK; ++c) {
    if (prod) {
      float* zb = &zbuf[c & 1][0][0];
#pragma unroll
      for (int tloc = 0; tloc < CHUNK; ++tloc) {
        const int t = c * CHUNK + tloc;
        int tl = t + 8;
        tl = tl < T_LEN ? tl : T_LEN - 1;  // clamped tail prefetch
        const float4 xqA = xrA[tloc & 7];
        xrA[tloc & 7] = xpA[(size_t)tl * (B_SZ * 4)];
        zb[tloc * (64 * NC) + col] = xdot(xqA);
        const float4 xqB = xrB[tloc & 7];
        xrB[tloc & 7] = xpB[(size_t)tl * (B_SZ * 4)];
        zb[tloc * (64 * NC) + col + 64] = xdot(xqB);
      }
    }

    __syncthreads();  // all 3 waves, same textual barrier, NCHUNK times

    if (!prod) {
      const float* zb = &zbuf[c & 1][0][0];
#pragma unroll
      for (int qq = 0; qq < CHUNK / 8; ++qq) {
        float hb[NC][8];
#pragma unroll
        for (int u = 0; u < 8; ++u) {
          const int tloc = (qq << 3) + u;
#pragma unroll
          for (int j = 0; j < NC; ++j) {
            const float zxf = zb[tloc * (64 * NC) + (j << 6) + lane];

            // recurrent dot: single-hop rotations (independent), depth-3 tree
            const float h1 = dppf<DPP_ROW_ROR(12)>(hx[j]);  // h_{w+1}
            const float h2 = dppf<DPP_ROW_ROR(8)>(hx[j]);   // h_{w+2}
            const float h3 = dppf<DPP_ROW_ROR(4)>(hx[j]);   // h_{w+3}
            float za = fmaf(Whs[0], hx[j], zxf);
            za = fmaf(Whs[1], h1, za);
            const float zb2 = fmaf(Whs[3], h3, Whs[2] * h2);
            const float z = za + zb2;  // in (-0.3, 1.3) revolutions

            const float ccos = __builtin_amdgcn_cosf(z);

            // inclusive cumprod over w: row_shr scan with identity-1 fill
            float q = ccos * dppf_id1<DPP_ROW_SHR(4)>(ccos);
            q = q * dppf_id1<DPP_ROW_SHR(8)>(q);

            // sigmoid (f,i,o) / tanh (g) via exp2+rcp, per-lane consts
            const float ee = __builtin_amdgcn_exp2f(q * nlscale);
            const float s = fmaf(__builtin_amdgcn_rcpf(1.0f + ee), nla, nlb);

            // gate all-gather: quad broadcasts
            const float fA = dppf<DPP_BCAST0>(s);
            const float iA = dppf<DPP_BCAST1>(s);
            const float gA = dppf<DPP_BCAST2>(s);
            const float oA = dppf<DPP_BCAST3>(s);

            cx[j] = fmaf(fA, cx[j], iA * gA);
            const float e3 = __builtin_amdgcn_exp2f(cx[j] * (-2.0f * L2E));
            const float th =
                fmaf(2.0f, __builtin_amdgcn_rcpf(1.0f + e3), -1.0f);
            hx[j] = oA * th;
            hb[j][u] = hx[j];
          }
        }
        // store burst: one exec-mask section per 8 timesteps
        if (g == 0) {
          const int tbase = c * CHUNK + (qq << 3);
#pragma unroll
          for (int j = 0; j < NC; ++j)
#pragma unroll
            for (int u = 0; u < 8; ++u)
              outp[j][(size_t)(tbase + u) * (B_SZ * 4)] = hb[j][u];
        }
      }
    }
  }

  if (!prod && g == 0) {
    const size_t base = (size_t)T_LEN * B_SZ * 4;
#pragma unroll
    for (int j = 0; j < NC; ++j) {
      out[base + ((b0 + 4 * j) << 2) + w] = hx[j];             // final hx
      out[base + B_SZ * 4 + ((b0 + 4 * j) << 2) + w] = cx[j];  // final cx
    }
  }
}

extern "C" void kernel_launch(void* const* d_in, const int* in_sizes, int n_in,
                              void* d_out, int out_size, void* d_ws, size_t ws_size,
                              hipStream_t stream) {
  const float* x   = (const float*)d_in[0];
  const float* Wf  = (const float*)d_in[1];
  const float* bf_ = (const float*)d_in[2];
  const float* Wi  = (const float*)d_in[3];
  const float* bi_ = (const float*)d_in[4];
  const float* Wg  = (const float*)d_in[5];
  const float* bg_ = (const float*)d_in[6];
  const float* Wo  = (const float*)d_in[7];
  const float* bo_ = (const float*)d_in[8];
  const float* rxf = (const float*)d_in[9];
  const float* rxi = (const float*)d_in[10];
  const float* rxg = (const float*)d_in[11];
  const float* rxo = (const float*)d_in[12];

  // 4096 batch / 16 per block = 256 blocks x 192 threads (3 waves:
  // wave0 = 4-chain recurrence consumer, waves1-2 = 2-chain producers)
  qlstm_65481071402744_kernel<<<B_SZ / 16, 192, 0, stream>>>(
      x, Wf, bf_, Wi, bi_, Wg, bg_, Wo, bo_, rxf, rxi, rxg, rxo,
      (float*)d_out);
}